// Round 3
// baseline (245.241 us; speedup 1.0000x reference)
//
#include <hip/hip_runtime.h>

// Reference folds to: S0 = sum(inp); m = S0>0 ? 2^64 : (S0<0 ? -2^63 : 2^32);
// out = m * inp.  (m is an exact power of two in every case.)
//
// Derivation: each iter does b=3a; s=sum(b); a := (s>0) ? a+b : a-b,
// i.e. a := 4a if sum(3a)>0 else -2a.  The array stays a scalar multiple
// of inp, so the branch depends only on sign(m*S0):
//   S0>0  -> '+' every iter           -> m = 4^32  = 2^64
//   S0<0  -> '-' once (m flips sign), then '+' 31x -> m = -2*4^31 = -2^63
//   S0==0 -> '-' every iter           -> m = (-2)^32 = 2^32

#define RGRID 2048   // reduce grid = number of partial slots in ws

__global__ __launch_bounds__(256) void reduce_sum_kernel(
        const float4* __restrict__ in, float* __restrict__ partials, int n4) {
    int tid    = blockIdx.x * blockDim.x + threadIdx.x;
    int stride = gridDim.x * blockDim.x;
    float s = 0.0f;
    for (int i = tid; i < n4; i += stride) {
        float4 v = in[i];
        s += (v.x + v.y) + (v.z + v.w);
    }
    // wave64 shuffle reduction
    #pragma unroll
    for (int off = 32; off > 0; off >>= 1)
        s += __shfl_down(s, off, 64);
    __shared__ float lds[4];
    int lane = threadIdx.x & 63;
    int wid  = threadIdx.x >> 6;
    if (lane == 0) lds[wid] = s;
    __syncthreads();
    if (threadIdx.x == 0) {
        // each block owns its slot: no atomic, no pre-zero of ws needed
        partials[blockIdx.x] = (lds[0] + lds[1]) + (lds[2] + lds[3]);
    }
}

__global__ __launch_bounds__(256) void scale_kernel(
        const float4* __restrict__ in, float4* __restrict__ out,
        const float* __restrict__ partials, int n4) {
    // Every block redundantly reduces the RGRID partials (8 KB, L2-hit).
    int lane = threadIdx.x & 63;
    float s = 0.0f;
    #pragma unroll
    for (int j = 0; j < RGRID / 64; ++j)
        s += partials[j * 64 + lane];
    #pragma unroll
    for (int off = 32; off > 0; off >>= 1)
        s += __shfl_down(s, off, 64);
    float S = __shfl(s, 0, 64);   // broadcast lane 0 to the wave

    float m = (S > 0.0f) ? 0x1p64f : ((S < 0.0f) ? -0x1p63f : 0x1p32f);
    int tid    = blockIdx.x * blockDim.x + threadIdx.x;
    int stride = gridDim.x * blockDim.x;
    for (int i = tid; i < n4; i += stride) {
        float4 v = in[i];
        v.x *= m; v.y *= m; v.z *= m; v.w *= m;
        out[i] = v;
    }
}

extern "C" void kernel_launch(void* const* d_in, const int* in_sizes, int n_in,
                              void* d_out, int out_size, void* d_ws, size_t ws_size,
                              hipStream_t stream) {
    const float* in = (const float*)d_in[0];
    float* out      = (float*)d_out;
    float* ws       = (float*)d_ws;   // >= RGRID floats of scratch
    int n  = in_sizes[0];             // 32*1024*1024, divisible by 4
    int n4 = n >> 2;

    const int BLK = 256;
    reduce_sum_kernel<<<RGRID, BLK, 0, stream>>>((const float4*)in, ws, n4);
    scale_kernel<<<RGRID, BLK, 0, stream>>>((const float4*)in, (float4*)out, ws, n4);
}

// Round 4
// 231.825 us; speedup vs baseline: 1.0579x; 1.0579x over previous
//
#include <hip/hip_runtime.h>

// Reference folds to: S0 = sum(inp); m = S0>0 ? 2^64 : (S0<0 ? -2^63 : 2^32);
// out = m * inp  (m exact power of two; absmax 0.0 verified in round 3).
//
// This round: branch SPECULATION. Pass 1 fuses the reduction with the
// speculative scale out = 2^64 * in (guessing S0 > 0), writing per-block
// partial sums. Pass 2 reduces the 2048 partials (8 KB, L2-hit) and only
// if the true sign differs from the guess rescales out by an exact
// power-of-two correction: S0<0 -> *-0.5, S0==0 -> *2^-32.
// Same work every call (flag is derived from restored-pristine input data).

#define RGRID 2048   // pass-1 grid = number of partial slots in ws
#define BLK   256

__global__ __launch_bounds__(256) void fused_reduce_scale_kernel(
        const float4* __restrict__ in, float4* __restrict__ out,
        float* __restrict__ partials, int n4) {
    int tid    = blockIdx.x * blockDim.x + threadIdx.x;
    int stride = gridDim.x * blockDim.x;
    const float m = 0x1p64f;           // speculate S0 > 0
    float s = 0.0f;
    for (int i = tid; i < n4; i += stride) {
        float4 v = in[i];
        s += (v.x + v.y) + (v.z + v.w);
        float4 w;
        w.x = v.x * m; w.y = v.y * m; w.z = v.z * m; w.w = v.w * m;
        out[i] = w;
    }
    // wave64 shuffle reduction
    #pragma unroll
    for (int off = 32; off > 0; off >>= 1)
        s += __shfl_down(s, off, 64);
    __shared__ float lds[4];
    int lane = threadIdx.x & 63;
    int wid  = threadIdx.x >> 6;
    if (lane == 0) lds[wid] = s;
    __syncthreads();
    if (threadIdx.x == 0)
        partials[blockIdx.x] = (lds[0] + lds[1]) + (lds[2] + lds[3]);
}

__global__ __launch_bounds__(256) void fixup_kernel(
        float4* __restrict__ out, const float* __restrict__ partials, int n4) {
    // Every block redundantly reduces the RGRID partials (8 KB, L2-hit).
    int lane = threadIdx.x & 63;
    float s = 0.0f;
    #pragma unroll
    for (int j = 0; j < RGRID / 64; ++j)
        s += partials[j * 64 + lane];
    #pragma unroll
    for (int off = 32; off > 0; off >>= 1)
        s += __shfl_down(s, off, 64);
    float S = __shfl(s, 0, 64);        // broadcast lane 0

    // correction factor vs speculated 2^64 (all exact powers of two)
    float f = (S > 0.0f) ? 1.0f : ((S < 0.0f) ? -0x1p-1f : 0x1p-32f);
    if (f == 1.0f) return;             // speculation held: ~5 us exit

    int tid    = blockIdx.x * blockDim.x + threadIdx.x;
    int stride = gridDim.x * blockDim.x;
    for (int i = tid; i < n4; i += stride) {
        float4 v = out[i];
        v.x *= f; v.y *= f; v.z *= f; v.w *= f;
        out[i] = v;
    }
}

extern "C" void kernel_launch(void* const* d_in, const int* in_sizes, int n_in,
                              void* d_out, int out_size, void* d_ws, size_t ws_size,
                              hipStream_t stream) {
    const float* in = (const float*)d_in[0];
    float* out      = (float*)d_out;
    float* ws       = (float*)d_ws;    // >= RGRID floats of scratch
    int n  = in_sizes[0];              // 32*1024*1024, divisible by 4
    int n4 = n >> 2;

    fused_reduce_scale_kernel<<<RGRID, BLK, 0, stream>>>(
        (const float4*)in, (float4*)out, ws, n4);
    fixup_kernel<<<RGRID, BLK, 0, stream>>>(
        (float4*)out, ws, n4);
}